// Round 13
// baseline (154.024 us; speedup 1.0000x reference)
//
#include <hip/hip_runtime.h>
#include <math.h>

typedef __attribute__((ext_vector_type(8))) short short8;
typedef __attribute__((ext_vector_type(16))) float f32x16;
typedef __attribute__((ext_vector_type(4))) unsigned uintx4;

#define XSTR 72        // shorts per (row,col) cell: 64 ci + 8 pad -> 144 B
#define NROWS 6        // rows staged per strip: i0-1 .. i0+4

__device__ __forceinline__ short f2bf(float f) {
    union { float f; unsigned u; } v; v.f = f;
    unsigned r = (v.u + 0x7FFFu + ((v.u >> 16) & 1u)) >> 16;
    return (short)r;
}

// packed f32x2 -> bf16x2 (RNE on gfx950)
__device__ __forceinline__ unsigned cvt_pk_bf16(float lo, float hi) {
    unsigned r;
    asm("v_cvt_pk_bf16_f32 %0, %1, %2" : "=v"(r) : "v"(lo), "v"(hi));
    return r;
}

// Barrier draining LDS ops only (no vmcnt(0) like __syncthreads).
__device__ __forceinline__ void bar_lds() {
    asm volatile("s_waitcnt lgkmcnt(0)" ::: "memory");
    __builtin_amdgcn_s_barrier();
}

// Build weight A-fragments (wfrag[p][q][lane][j], p=ph*2+pw, q=tap*4+ci_blk);
// tail block zeroes the accumulator and the 16 per-image counters.
__global__ void prep(const float* __restrict__ w, short* __restrict__ wfrag,
                     float* __restrict__ acc, unsigned* __restrict__ ctr) {
    if (blockIdx.x >= 128) {
        #pragma unroll
        for (int i = 0; i < 16; ++i) acc[i * 256 + threadIdx.x] = 0.f;
        if (threadIdx.x < 16) ctr[threadIdx.x] = 0u;
        return;
    }
    int idx = blockIdx.x * 256 + threadIdx.x;   // 0 .. 32767
    int j    = idx & 7;
    int lane = (idx >> 3) & 63;
    int q    = (idx >> 9) & 15;
    int p    = idx >> 13;
    int co = lane & 31, hf = lane >> 5;
    int ci = (q & 3) * 16 + hf * 8 + j;
    int tq = q >> 2, a = tq >> 1, b = tq & 1;
    int ph = p >> 1, pw = p & 1;
    int kh = 2 * a + 1 - ph, kw = 2 * b + 1 - pw;
    wfrag[idx] = f2bf(w[((ci * 32 + co) * 4 + kh) * 4 + kw]);
}

// Block = (n, row strip st [4 input rows]) x FULL 128-col width.
// 112.3 KB dynamic LDS (exceeds the 64 KB static ceiling that forced
// narrow tiles). Grid 512 -> 2 sequential rounds/CU (vs R12's 4 -- the
// measured binding factor). NO column-halo gathers: pad cols are zero
// ds_writes; row OOB zeroed. Staging: 192 coalesced loads/thread, depth-2
// row pipeline, af/cb last. One LDS barrier, 2 barrier-free MFMA steps x
// 4 col-quarters (both row-pairs interleaved, shared middle row).
// Epilogue: device-scope atomicAdd column sums; 32nd block per image
// applies GELU+bias (fused finalize).
__global__ __launch_bounds__(256, 2) void convt_mfma(
    const float* __restrict__ x, const short* __restrict__ wfrag,
    const float* __restrict__ conv_b, float* __restrict__ acc,
    unsigned* __restrict__ ctr, const float* __restrict__ bias,
    float* __restrict__ out)
{
    extern __shared__ short xs[];            // [NROWS][130][XSTR] = 112,320 B
    __shared__ float minbuf[4][128];         // [wave][col], 2 KB static
    __shared__ unsigned lastf;

    // XCD-aware bijective swizzle (512 % 8 == 0)
    int blk = ((blockIdx.x & 7) << 6) | (blockIdx.x >> 3);
    const int n = blk >> 5, st = blk & 31;
    const int t  = threadIdx.x;
    const int i0 = st * 4;

    const int wv = t >> 6, lane = t & 63;    // wave = output parity (ph,pw)
    const int ph = wv >> 1, pw = wv & 1;
    const int ln = lane & 31, half = lane >> 5;

    const float* xn = x + (size_t)n * 64 * 128 * 128;
    const int col = t & 127;                 // full-width col
    const int cib = (t >> 7) * 32;           // 32 consecutive ci per thread

    // ---- staging: core rows, depth-2 pipeline; NO halo gathers ----
    float pfA[32], pfB[32];
    auto load_row = [&](int r, float* dst) {
        int gi = i0 - 1 + r;
        bool ok = (unsigned)gi < 128u;
        int gic = ok ? gi : 0;
        const float* px = xn + (size_t)cib * 16384 + gic * 128 + col;
        #pragma unroll
        for (int c = 0; c < 32; ++c) dst[c] = ok ? px[c * 16384] : 0.f;
    };
    auto write_row = [&](int r, const float* src) {
        short* dp = &xs[((size_t)r * 130 + col + 1) * XSTR + cib];
        #pragma unroll
        for (int g = 0; g < 4; ++g) {
            uintx4 u;
            u.x = cvt_pk_bf16(src[g*8+0], src[g*8+1]);
            u.y = cvt_pk_bf16(src[g*8+2], src[g*8+3]);
            u.z = cvt_pk_bf16(src[g*8+4], src[g*8+5]);
            u.w = cvt_pk_bf16(src[g*8+6], src[g*8+7]);
            *(uintx4*)(dp + g * 8) = u;
        }
    };
    load_row(0, pfA);
    load_row(1, pfB);
    write_row(0, pfA); load_row(2, pfA);
    write_row(1, pfB); load_row(3, pfB);
    write_row(2, pfA); load_row(4, pfA);
    write_row(3, pfB); load_row(5, pfB);
    write_row(4, pfA);
    write_row(5, pfB);

    // zero pad columns (pcol 0 and 129): pure LDS writes, no global access
    if (t < 32) {
        int side = t >> 4, c4 = (t & 15) * 4;
        #pragma unroll
        for (int r = 0; r < NROWS; ++r)
            *(unsigned long long*)&xs[((size_t)r * 130 + (side ? 129 : 0)) * XSTR + c4] = 0ULL;
    }

    // A fragments + conv-bias seed, issued last
    short8 af[16];
    {
        const short8* wf = (const short8*)(wfrag + wv * 8192);
        #pragma unroll
        for (int q = 0; q < 16; ++q) af[q] = wf[q * 64 + lane];
    }
    float cb[16];
    #pragma unroll
    for (int reg = 0; reg < 16; ++reg)
        cb[reg] = conv_b[(reg & 3) + 8 * (reg >> 2) + 4 * half];

    bar_lds();

    // ---- 2 compute steps x 4 col-quarters: wave-local, barrier-free ----
    float osum[4] = {0.f, 0.f, 0.f, 0.f};
    #pragma unroll
    for (int k = 0; k < 2; ++k) {
        const int L0 = 2 * k + ph;           // rows L0, L0+1 (shared), L0+2
        #pragma unroll
        for (int jb = 0; jb < 4; ++jb) {
            f32x16 acc0, acc1;
            #pragma unroll
            for (int reg = 0; reg < 16; ++reg) { acc0[reg] = cb[reg]; acc1[reg] = cb[reg]; }
            __builtin_amdgcn_s_setprio(1);
            #pragma unroll
            for (int b = 0; b < 2; ++b) {
                int colp = jb * 32 + ln + (pw - b) + 1;
                const short* p0 = &xs[((size_t)(L0    ) * 130 + colp) * XSTR + half * 8];
                const short* p1 = &xs[((size_t)(L0 + 1) * 130 + colp) * XSTR + half * 8];
                const short* p2 = &xs[((size_t)(L0 + 2) * 130 + colp) * XSTR + half * 8];
                #pragma unroll
                for (int c = 0; c < 4; ++c) {
                    short8 Fs = *(const short8*)(p1 + c * 16);   // shared middle row
                    acc0 = __builtin_amdgcn_mfma_f32_32x32x16_bf16(af[4*b+c],   Fs, acc0, 0, 0, 0);
                    acc1 = __builtin_amdgcn_mfma_f32_32x32x16_bf16(af[8+4*b+c], Fs, acc1, 0, 0, 0);
                    short8 F0 = *(const short8*)(p0 + c * 16);
                    acc0 = __builtin_amdgcn_mfma_f32_32x32x16_bf16(af[8+4*b+c], F0, acc0, 0, 0, 0);
                    short8 F2 = *(const short8*)(p2 + c * 16);
                    acc1 = __builtin_amdgcn_mfma_f32_32x32x16_bf16(af[4*b+c],   F2, acc1, 0, 0, 0);
                }
            }
            __builtin_amdgcn_s_setprio(0);

            // tree min-reduce over co (16 acc rows), both row-pairs
            float mn0, mn1;
            {
                float a = fminf(fminf(acc0[0], acc0[1]), fminf(acc0[2], acc0[3]));
                float b2 = fminf(fminf(acc0[4], acc0[5]), fminf(acc0[6], acc0[7]));
                float c = fminf(fminf(acc0[8], acc0[9]), fminf(acc0[10], acc0[11]));
                float d = fminf(fminf(acc0[12], acc0[13]), fminf(acc0[14], acc0[15]));
                mn0 = fminf(fminf(a, b2), fminf(c, d));
                a = fminf(fminf(acc1[0], acc1[1]), fminf(acc1[2], acc1[3]));
                b2 = fminf(fminf(acc1[4], acc1[5]), fminf(acc1[6], acc1[7]));
                c = fminf(fminf(acc1[8], acc1[9]), fminf(acc1[10], acc1[11]));
                d = fminf(fminf(acc1[12], acc1[13]), fminf(acc1[14], acc1[15]));
                mn1 = fminf(fminf(a, b2), fminf(c, d));
            }
            mn0 = fminf(mn0, __shfl_xor(mn0, 32, 64));   // fold co halves
            mn1 = fminf(mn1, __shfl_xor(mn1, 32, 64));
            osum[jb] += mn0 + mn1;                       // height-sum (linear)
        }
    }

    if (half == 0) {
        #pragma unroll
        for (int jb = 0; jb < 4; ++jb) minbuf[wv][jb * 32 + ln] = osum[jb];
    }
    bar_lds();

    // combine ph=0 + ph=1 per pw -> one device-scope atomicAdd per column
    {
        int c = t & 127, pwp = t >> 7;
        float v = minbuf[pwp][c] + minbuf[2 + pwp][c];
        int ow = (c << 1) | pwp;
        atomicAdd(&acc[n * 256 + ow], v);
    }
    __syncthreads();    // drains each wave's vmcnt(0): atomics globally done
    if (t == 0) lastf = (atomicAdd(&ctr[n], 1u) == 31u) ? 1u : 0u;
    __syncthreads();

    // 32nd block of image n: GELU+bias on its 256 sums (fused finalize)
    if (lastf) {
        __threadfence();   // acquire (single block only)
        float s = __hip_atomic_load(&acc[n * 256 + t], __ATOMIC_RELAXED,
                                    __HIP_MEMORY_SCOPE_AGENT);
        float u = 0.7978845608028654f * (s + 0.044715f * s * s * s);
        out[n * 256 + t] = 0.5f * s * (1.f + tanhf(u)) + bias[0];
    }
}

extern "C" void kernel_launch(void* const* d_in, const int* in_sizes, int n_in,
                              void* d_out, int out_size, void* d_ws, size_t ws_size,
                              hipStream_t stream) {
    const float* x      = (const float*)d_in[0];   // [16,64,128,128]
    const float* w      = (const float*)d_in[1];   // [64,32,4,4]
    const float* conv_b = (const float*)d_in[2];   // [32]
    const float* bias   = (const float*)d_in[3];   // [1]
    float* out = (float*)d_out;                    // 16*256

    short*    wfrag = (short*)d_ws;                          // 64 KB
    float*    acc   = (float*)((char*)d_ws + 65536);         // 16 KB
    unsigned* ctr   = (unsigned*)((char*)d_ws + 65536 + 16384);  // 64 B

    hipLaunchKernelGGL(prep, dim3(129), dim3(256), 0, stream, w, wfrag, acc, ctr);
    hipLaunchKernelGGL(convt_mfma, dim3(512), dim3(256),
                       NROWS * 130 * XSTR * sizeof(short), stream,
                       x, wfrag, conv_b, acc, ctr, bias, out);
}